// Round 1
// baseline (1546.434 us; speedup 1.0000x reference)
//
#include <hip/hip_runtime.h>

// Problem constants
#define M_ROWS 16384   // 32*512 z vectors
#define N_CB   8192    // codebook entries
#define KDIM   256     // code dim

// GEMM tiling
#define BM 64
#define BN 128
#define BK 16
#define TM 4
#define TN 8
#define NSPLIT 4
#define CODES_PER_SPLIT (N_CB / NSPLIT)      // 2048
#define CT_PER_SPLIT (CODES_PER_SPLIT / BN)  // 16
#define KC_COUNT (KDIM / BK)                 // 16

#define FLTMAX 3.402823466e+38f

// ---------------- zero counts ----------------
__global__ __launch_bounds__(256) void zero_counts_kernel(int* counts) {
  int g = blockIdx.x * 256 + threadIdx.x;
  if (g < N_CB) counts[g] = 0;
}

// ---------------- row squared norms (one wave per row) ----------------
__global__ __launch_bounds__(256) void rowsq_kernel(const float4* __restrict__ ze4,
                                                    const float4* __restrict__ cb4,
                                                    float* __restrict__ z2,
                                                    float* __restrict__ e2) {
  int wave = blockIdx.x * 4 + (threadIdx.x >> 6);
  int lane = threadIdx.x & 63;
  float4 v;
  if (wave < M_ROWS) v = ze4[(size_t)wave * 64 + lane];
  else               v = cb4[(size_t)(wave - M_ROWS) * 64 + lane];
  float s = v.x * v.x + v.y * v.y + v.z * v.z + v.w * v.w;
  #pragma unroll
  for (int off = 32; off > 0; off >>= 1) s += __shfl_down(s, off, 64);
  if (lane == 0) {
    if (wave < M_ROWS) z2[wave] = s;
    else               e2[wave - M_ROWS] = s;
  }
}

// ---------------- fused distance GEMM + argmin ----------------
// dist = fl(fl(z2 + e2) - fl(2*dot)) to replicate reference fp32 rounding;
// argmin tie rule: smallest value, then smallest code index.
__global__ __launch_bounds__(256, 4) void dist_argmin_kernel(
    const float* __restrict__ A,   // z_e  (M_ROWS x KDIM)
    const float* __restrict__ B,   // codebook (N_CB x KDIM)
    const float* __restrict__ z2,
    const float* __restrict__ e2,
    float* __restrict__ pval,      // NSPLIT x M_ROWS partial min values
    int* __restrict__ pidx) {      // NSPLIT x M_ROWS partial argmin
  __shared__ float As[BK][BM + 4];   // transposed: [k][m]
  __shared__ float Bs[BK][BN + 4];   // transposed: [k][n]
  __shared__ float redv[BM][17];
  __shared__ int   redi[BM][17];

  const int tid = threadIdx.x;
  const int tx = tid & 15;        // code dim, 8 codes each
  const int ty = tid >> 4;        // row dim, 4 rows each
  const int mb = blockIdx.x * BM;
  const int nb0 = blockIdx.y * CODES_PER_SPLIT;

  // global->LDS load mapping
  const int arow = tid >> 2, akq = tid & 3;                 // A: 1 float4 / thread
  const int brow0 = tid >> 1, bkq0 = (tid * 2) & 3;          // B: 2 float4 / thread
  const int brow1 = (tid * 2 + 1) >> 2, bkq1 = (tid * 2 + 1) & 3;

  const float* Abase = A + (size_t)(mb + arow) * KDIM + akq * 4;

  float z2r[TM];
  #pragma unroll
  for (int i = 0; i < TM; i++) z2r[i] = z2[mb + ty * TM + i];

  float bestv[TM]; int besti[TM];
  #pragma unroll
  for (int i = 0; i < TM; i++) { bestv[i] = FLTMAX; besti[i] = 0; }

  for (int ct = 0; ct < CT_PER_SPLIT; ct++) {
    const int nb = nb0 + ct * BN;
    const float* Bbase = B + (size_t)nb * KDIM;

    float acc[TM][TN];
    #pragma unroll
    for (int i = 0; i < TM; i++)
      #pragma unroll
      for (int j = 0; j < TN; j++) acc[i][j] = 0.0f;

    // prefetch first k-chunk into registers
    float4 pa  = *(const float4*)(Abase);
    float4 pb0 = *(const float4*)(Bbase + (size_t)brow0 * KDIM + bkq0 * 4);
    float4 pb1 = *(const float4*)(Bbase + (size_t)brow1 * KDIM + bkq1 * 4);

    for (int kc = 0; kc < KC_COUNT; kc++) {
      __syncthreads();   // previous compute done; LDS free to overwrite
      As[akq * 4 + 0][arow] = pa.x;
      As[akq * 4 + 1][arow] = pa.y;
      As[akq * 4 + 2][arow] = pa.z;
      As[akq * 4 + 3][arow] = pa.w;
      Bs[bkq0 * 4 + 0][brow0] = pb0.x;
      Bs[bkq0 * 4 + 1][brow0] = pb0.y;
      Bs[bkq0 * 4 + 2][brow0] = pb0.z;
      Bs[bkq0 * 4 + 3][brow0] = pb0.w;
      Bs[bkq1 * 4 + 0][brow1] = pb1.x;
      Bs[bkq1 * 4 + 1][brow1] = pb1.y;
      Bs[bkq1 * 4 + 2][brow1] = pb1.z;
      Bs[bkq1 * 4 + 3][brow1] = pb1.w;
      __syncthreads();
      if (kc + 1 < KC_COUNT) {   // prefetch next chunk, overlaps compute
        pa  = *(const float4*)(Abase + (kc + 1) * BK);
        pb0 = *(const float4*)(Bbase + (size_t)brow0 * KDIM + (kc + 1) * BK + bkq0 * 4);
        pb1 = *(const float4*)(Bbase + (size_t)brow1 * KDIM + (kc + 1) * BK + bkq1 * 4);
      }
      #pragma unroll
      for (int k = 0; k < BK; k++) {
        float4 a4  = *(const float4*)&As[k][ty * TM];
        float4 b4a = *(const float4*)&Bs[k][tx * TN];
        float4 b4b = *(const float4*)&Bs[k][tx * TN + 4];
        float af[TM] = {a4.x, a4.y, a4.z, a4.w};
        float bf[TN] = {b4a.x, b4a.y, b4a.z, b4a.w, b4b.x, b4b.y, b4b.z, b4b.w};
        #pragma unroll
        for (int i = 0; i < TM; i++)
          #pragma unroll
          for (int j = 0; j < TN; j++)
            acc[i][j] = fmaf(af[i], bf[j], acc[i][j]);
      }
    }

    // epilogue: distances + running argmin (codes ascending in j, then ct)
    float e2v[TN];
    #pragma unroll
    for (int j = 0; j < TN; j++) e2v[j] = e2[nb + tx * TN + j];
    #pragma unroll
    for (int i = 0; i < TM; i++) {
      #pragma unroll
      for (int j = 0; j < TN; j++) {
        float s = z2r[i] + e2v[j];           // fp32 round, as reference
        float dist = s - 2.0f * acc[i][j];   // 2*acc exact; single subtract round
        if (dist < bestv[i]) { bestv[i] = dist; besti[i] = nb + tx * TN + j; }
      }
    }
  }

  // cross-tx reduction per row (lexicographic: value, then code index)
  __syncthreads();
  #pragma unroll
  for (int i = 0; i < TM; i++) {
    redv[ty * TM + i][tx] = bestv[i];
    redi[ty * TM + i][tx] = besti[i];
  }
  __syncthreads();
  if (tid < BM) {
    float bv = redv[tid][0]; int bi = redi[tid][0];
    #pragma unroll
    for (int t = 1; t < 16; t++) {
      float v = redv[tid][t]; int i2 = redi[tid][t];
      if (v < bv || (v == bv && i2 < bi)) { bv = v; bi = i2; }
    }
    pval[(size_t)blockIdx.y * M_ROWS + mb + tid] = bv;
    pidx[(size_t)blockIdx.y * M_ROWS + mb + tid] = bi;
  }
}

// ---------------- merge split partials ----------------
__global__ __launch_bounds__(256) void merge_kernel(const float* __restrict__ pval,
                                                    const int* __restrict__ pidx,
                                                    int* __restrict__ idx_out,
                                                    float* __restrict__ codes_out) {
  int r = blockIdx.x * 256 + threadIdx.x;
  float bv = pval[r]; int bi = pidx[r];
  #pragma unroll
  for (int s = 1; s < NSPLIT; s++) {
    float v = pval[(size_t)s * M_ROWS + r];
    int i2  = pidx[(size_t)s * M_ROWS + r];
    if (v < bv || (v == bv && i2 < bi)) { bv = v; bi = i2; }
  }
  idx_out[r] = bi;
  codes_out[r] = (float)bi;
}

// ---------------- gather z_q, write z_q_st, loss partials, histogram ----------------
// One wave handles exactly one row (64 float4 per row).
__global__ __launch_bounds__(256) void gather_kernel(const float4* __restrict__ ze4,
                                                     const float4* __restrict__ cb4,
                                                     const int* __restrict__ idx,
                                                     float4* __restrict__ out4,
                                                     float* __restrict__ lpart,
                                                     int* __restrict__ counts) {
  int g = blockIdx.x * 256 + threadIdx.x;   // 0 .. 1048575
  int row = g >> 6;
  int c4 = g & 63;
  int lane = threadIdx.x & 63;
  int code = idx[row];
  float4 z = ze4[(size_t)row * 64 + c4];
  float4 e = cb4[(size_t)code * 64 + c4];
  float dx = e.x - z.x, dy = e.y - z.y, dz = e.z - z.z, dw = e.w - z.w;
  float4 o;
  o.x = z.x + dx; o.y = z.y + dy; o.z = z.z + dz; o.w = z.w + dw;  // z_e + (z_q - z_e)
  out4[(size_t)row * 64 + c4] = o;
  float ls = dx * dx + dy * dy + dz * dz + dw * dw;
  #pragma unroll
  for (int off = 32; off > 0; off >>= 1) ls += __shfl_down(ls, off, 64);
  __shared__ float sred[4];
  if (lane == 0) {
    sred[threadIdx.x >> 6] = ls;
    atomicAdd(&counts[code], 1);   // exactly one wave per row
  }
  __syncthreads();
  if (threadIdx.x == 0) lpart[blockIdx.x] = sred[0] + sred[1] + sred[2] + sred[3];
}

// ---------------- finalize scalars ----------------
__global__ __launch_bounds__(256) void finalize_kernel(const float* __restrict__ lpart,
                                                       const int* __restrict__ counts,
                                                       float* __restrict__ out_scalars) {
  __shared__ double sd[256];
  double s = 0.0;
  for (int i = threadIdx.x; i < 4096; i += 256) s += (double)lpart[i];
  sd[threadIdx.x] = s;
  __syncthreads();
  for (int st = 128; st > 0; st >>= 1) {
    if (threadIdx.x < st) sd[threadIdx.x] += sd[threadIdx.x + st];
    __syncthreads();
  }
  double totalLoss = sd[0];
  __syncthreads();
  double ps = 0.0;
  for (int c = threadIdx.x; c < N_CB; c += 256) {
    float avg = (float)counts[c] * (1.0f / 16384.0f);   // exact (div by 2^14)
    ps += (double)(avg * logf(avg + 1e-10f));
  }
  sd[threadIdx.x] = ps;
  __syncthreads();
  for (int st = 128; st > 0; st >>= 1) {
    if (threadIdx.x < st) sd[threadIdx.x] += sd[threadIdx.x + st];
    __syncthreads();
  }
  if (threadIdx.x == 0) {
    float mean = (float)(totalLoss / 4194304.0);  // mean over 16384*256 elements
    float lv = mean + 0.25f * mean;               // loss_cb + BETA*loss_commit (equal values)
    out_scalars[0] = lv;
    out_scalars[1] = expf(-(float)sd[0]);
  }
}

extern "C" void kernel_launch(void* const* d_in, const int* in_sizes, int n_in,
                              void* d_out, int out_size, void* d_ws, size_t ws_size,
                              hipStream_t stream) {
  const float* z_e = (const float*)d_in[0];   // 32*512*256
  const float* cb  = (const float*)d_in[1];   // 8192*256
  float* out = (float*)d_out;
  // out layout: [0,4194304) z_q_st | [4194304,4210688) codes(float) | loss | perplexity

  char* ws = (char*)d_ws;
  float* z2     = (float*)(ws + 0);         // 16384 f32
  float* e2     = (float*)(ws + 65536);     // 8192 f32
  float* pval   = (float*)(ws + 98304);     // NSPLIT*16384 f32 (262144 B)
  int*   pidx   = (int*)  (ws + 360448);    // NSPLIT*16384 i32 (262144 B)
  int*   idxf   = (int*)  (ws + 622592);    // 16384 i32
  int*   counts = (int*)  (ws + 688128);    // 8192 i32
  float* lpart  = (float*)(ws + 720896);    // 4096 f32
  // total ws use: ~738 KB

  zero_counts_kernel<<<32, 256, 0, stream>>>(counts);
  rowsq_kernel<<<(M_ROWS + N_CB) / 4, 256, 0, stream>>>(
      (const float4*)z_e, (const float4*)cb, z2, e2);
  dim3 grid(M_ROWS / BM, NSPLIT);
  dist_argmin_kernel<<<grid, 256, 0, stream>>>(z_e, cb, z2, e2, pval, pidx);
  merge_kernel<<<M_ROWS / 256, 256, 0, stream>>>(pval, pidx, idxf, out + 4194304);
  gather_kernel<<<4096, 256, 0, stream>>>((const float4*)z_e, (const float4*)cb, idxf,
                                          (float4*)out, lpart, counts);
  finalize_kernel<<<1, 256, 0, stream>>>(lpart, counts, out + 4210688);
}